// Round 1
// 340.374 us; speedup vs baseline: 1.0276x; 1.0276x over previous
//
#include <hip/hip_runtime.h>
#include <stdint.h>

typedef __bf16 bf16_t;
typedef bf16_t bf16x8 __attribute__((ext_vector_type(8)));
typedef float f32x4 __attribute__((ext_vector_type(4)));
typedef float f32x16 __attribute__((ext_vector_type(16)));

__device__ __forceinline__ unsigned short f2bf(float x) {
    unsigned u = __builtin_bit_cast(unsigned, x);
    u = (u + 0x7FFFu + ((u >> 16) & 1u)) >> 16;   // RNE
    return (unsigned short)u;
}

// pack two fp32 -> bf16x2 (round-half-up): 2 adds + 1 v_perm
__device__ __forceinline__ unsigned pk_bf16(float lo, float hi) {
    unsigned u0 = __builtin_bit_cast(unsigned, lo) + 0x8000u;
    unsigned u1 = __builtin_bit_cast(unsigned, hi) + 0x8000u;
    return __builtin_amdgcn_perm(u1, u0, 0x07060302u);
}

// CK-pattern async global->LDS, 16B per lane. LDS dest must be wave-uniform.
__device__ __forceinline__ void async_load16(const void* g, void* lds) {
    auto* gp = reinterpret_cast<const __attribute__((address_space(1))) uint32_t*>(
        reinterpret_cast<uintptr_t>(g));
    auto* lp = reinterpret_cast<__attribute__((address_space(3))) uint32_t*>(
        reinterpret_cast<uintptr_t>(lds));
    __builtin_amdgcn_global_load_lds(gp, lp, 16, 0, 0);
}

// ---------------- cast fp32 -> bf16, 8 elems/thread ----------------
__global__ __launch_bounds__(256) void cast_f32_bf16(const float* __restrict__ src,
                                                     unsigned short* __restrict__ dst,
                                                     int n8) {
    int i = blockIdx.x * 256 + threadIdx.x;
    if (i >= n8) return;
    const float4* s4 = (const float4*)src;
    float4 a = s4[i * 2], b = s4[i * 2 + 1];
    uint4 o;
    o.x = (unsigned)f2bf(a.x) | ((unsigned)f2bf(a.y) << 16);
    o.y = (unsigned)f2bf(a.z) | ((unsigned)f2bf(a.w) << 16);
    o.z = (unsigned)f2bf(b.x) | ((unsigned)f2bf(b.y) << 16);
    o.w = (unsigned)f2bf(b.z) | ((unsigned)f2bf(b.w) << 16);
    ((uint4*)dst)[i] = o;
}

// ---------------- transpose-cast: src [K][N] fp32 -> dst [N][K] bf16, * scale ----------------
__global__ __launch_bounds__(256) void transcast(const float* __restrict__ src,
                                                 unsigned short* __restrict__ dst,
                                                 int K, int N, float scale) {
    __shared__ float tile[32][33];
    int x = threadIdx.x, y = threadIdx.y;          // block (32,8)
    int c0 = blockIdx.x * 32, r0 = blockIdx.y * 32;
    #pragma unroll
    for (int i = 0; i < 32; i += 8)
        tile[y + i][x] = src[(size_t)(r0 + y + i) * N + c0 + x];
    __syncthreads();
    #pragma unroll
    for (int i = 0; i < 32; i += 8)
        dst[(size_t)(c0 + y + i) * K + r0 + x] = f2bf(tile[x][y + i] * scale);
}

// ---------------- C = A[M,K] * Bt[N,K]^T, bf16 MFMA, 128x128 tile, BK=64 ----------------
// Double-buffered LDS, prefetch-next-before-compute (T3 minimal 2-phase):
// load latency hides under the 32 MFMAs instead of being drained between barriers.
// EPI 0: bf16 out, stride N.  EPI 2: f32 out + bias.
template <int EPI>
__global__ __launch_bounds__(256) void gemm_bt(const unsigned short* __restrict__ A,
                                               const unsigned short* __restrict__ Bt,
                                               void* __restrict__ Cout,
                                               const float* __restrict__ bias,
                                               int K, int N, int nkt) {
    __shared__ __align__(16) unsigned short lA[2][128 * 64];  // 2 x 16 KB
    __shared__ __align__(16) unsigned short lB[2][128 * 64];  // 2 x 16 KB
    const int tid = threadIdx.x;
    const int w = tid >> 6, l = tid & 63;
    const int wm = w >> 1, wn = w & 1;
    const int row0 = blockIdx.y * 128, col0 = blockIdx.x * 128;
    const int lrow = l & 15, lq = l >> 4;
    const int srow = l >> 3;                 // 0..7: row within an issue's 8-row group
    const int scol = ((l & 7) ^ srow) * 8;   // XOR-swizzled k-chunk (elems)

    f32x4 acc[4][4];
    #pragma unroll
    for (int i = 0; i < 4; ++i)
        #pragma unroll
        for (int j = 0; j < 4; ++j) acc[i][j] = (f32x4)0.f;

    // hoisted per-q global source pointers; advance by 64 elems per staged tile
    const unsigned short* ga[4];
    const unsigned short* gb[4];
    #pragma unroll
    for (int q = 0; q < 4; ++q) {
        const int r = (w * 4 + q) * 8 + srow;
        ga[q] = A + (size_t)(row0 + r) * K + scol;
        gb[q] = Bt + (size_t)(col0 + r) * K + scol;
    }

    // prologue: stage kt=0 into buffer 0
    #pragma unroll
    for (int q = 0; q < 4; ++q) {
        async_load16(ga[q], (char*)lA + (w * 4 + q) * 1024);
        async_load16(gb[q], (char*)lB + (w * 4 + q) * 1024);
        ga[q] += 64;
        gb[q] += 64;
    }
    __syncthreads();

    for (int kt = 0; kt < nkt; ++kt) {
        const int bo = (kt & 1) * 16384;   // byte offset of current buffer
        if (kt + 1 < nkt) {
            const int bn = bo ^ 16384;
            #pragma unroll
            for (int q = 0; q < 4; ++q) {
                async_load16(ga[q], (char*)lA + bn + (w * 4 + q) * 1024);
                async_load16(gb[q], (char*)lB + bn + (w * 4 + q) * 1024);
                ga[q] += 64;
                gb[q] += 64;
            }
        }
        #pragma unroll
        for (int kc = 0; kc < 2; ++kc) {
            const int pc = ((kc * 4 + lq) ^ (lrow & 7)) * 16;  // byte offset of chunk
            bf16x8 af[4], bfr[4];
            #pragma unroll
            for (int i = 0; i < 4; ++i)
                af[i] = *(const bf16x8*)((const char*)lA + bo + (wm * 64 + i * 16 + lrow) * 128 + pc);
            #pragma unroll
            for (int j = 0; j < 4; ++j)
                bfr[j] = *(const bf16x8*)((const char*)lB + bo + (wn * 64 + j * 16 + lrow) * 128 + pc);
            #pragma unroll
            for (int i = 0; i < 4; ++i)
                #pragma unroll
                for (int j = 0; j < 4; ++j)
                    acc[i][j] = __builtin_amdgcn_mfma_f32_16x16x32_bf16(af[i], bfr[j],
                                                                        acc[i][j], 0, 0, 0);
        }
        __syncthreads();   // drains prefetch vmcnt; issued ~1 compute-phase earlier
    }
    #pragma unroll
    for (int i = 0; i < 4; ++i) {
        const int grow0 = row0 + wm * 64 + i * 16 + lq * 4;
        #pragma unroll
        for (int j = 0; j < 4; ++j) {
            const int gcol = col0 + wn * 64 + j * 16 + lrow;
            #pragma unroll
            for (int r = 0; r < 4; ++r) {
                float v = acc[i][j][r];
                int grow = grow0 + r;
                if (EPI == 0) {
                    ((unsigned short*)Cout)[(size_t)grow * N + gcol] = f2bf(v);
                } else {
                    ((float*)Cout)[(size_t)grow * N + gcol] = v + bias[gcol];
                }
            }
        }
    }
}

// ---------------- KV GEMM: 256x128 block, 32x32x16 MFMA, wave tile 128x64 ----------------
// A = cin [16384 x 768], Bt = wkvT [2048 x 768], K=768 (12 BK=64 tiles).
// cols<1024 -> Kb[b*2048+key][feat]; cols>=1024 -> Vt[(b*1024+fv)][key] packed dwordx2.
__global__ __launch_bounds__(256, 2) void gemm_kv(const unsigned short* __restrict__ A,
                                                  const unsigned short* __restrict__ Bt,
                                                  unsigned short* __restrict__ Kb,
                                                  unsigned short* __restrict__ Vt) {
    __shared__ __align__(16) unsigned short lA[256 * 64];  // 32 KB
    __shared__ __align__(16) unsigned short lB[128 * 64];  // 16 KB
    const int tid = threadIdx.x;
    const int w = tid >> 6, l = tid & 63;
    const int wm = w >> 1, wn = w & 1;
    const int row0 = blockIdx.y * 256, col0 = blockIdx.x * 128;
    const int r32 = l & 31, hw = l >> 5;
    const int srow = l >> 3, scol = ((l & 7) ^ srow) * 8;

    f32x16 acc[4][2];
    #pragma unroll
    for (int mi = 0; mi < 4; ++mi)
        #pragma unroll
        for (int ni = 0; ni < 2; ++ni) acc[mi][ni] = (f32x16)0.f;

    const unsigned short* ga = A + (size_t)(row0 + w * 8 + srow) * 768 + scol;
    const unsigned short* gb = Bt + (size_t)(col0 + w * 8 + srow) * 768 + scol;
    char* lAw = (char*)lA + (w * 8) * 128;
    char* lBw = (char*)lB + (w * 8) * 128;
    const char* lap = (const char*)lA + (wm * 128 + r32) * 128;
    const char* lbp = (const char*)lB + (wn * 64 + r32) * 128;
    const int r7 = r32 & 7;

    for (int kt = 0; kt < 12; ++kt) {
        __syncthreads();
        #pragma unroll
        for (int q = 0; q < 8; ++q)
            async_load16(ga + (size_t)q * 32 * 768, lAw + q * 32 * 128);
        #pragma unroll
        for (int q = 0; q < 4; ++q)
            async_load16(gb + (size_t)q * 32 * 768, lBw + q * 32 * 128);
        ga += 64;
        gb += 64;
        __syncthreads();
        #pragma unroll
        for (int ks = 0; ks < 4; ++ks) {
            const int off = ((ks * 2 + hw) ^ r7) * 16;  // byte offset of swizzled chunk
            bf16x8 af[4], bfr[2];
            #pragma unroll
            for (int mi = 0; mi < 4; ++mi)
                af[mi] = *(const bf16x8*)(lap + mi * 32 * 128 + off);
            #pragma unroll
            for (int ni = 0; ni < 2; ++ni)
                bfr[ni] = *(const bf16x8*)(lbp + ni * 32 * 128 + off);
            #pragma unroll
            for (int mi = 0; mi < 4; ++mi)
                #pragma unroll
                for (int ni = 0; ni < 2; ++ni)
                    acc[mi][ni] = __builtin_amdgcn_mfma_f32_32x32x16_bf16(af[mi], bfr[ni],
                                                                          acc[mi][ni], 0, 0, 0);
        }
    }

    // C/D 32x32 layout: col = lane&31, row = (reg&3) + 8*(reg>>2) + 4*(lane>>5)
    if (col0 < 1024) {
        // K half: Kb[(row0 + wm*128 + rr) * 1024 + col0 + wn*64 + ni*32 + r32]
        unsigned short* kp = Kb + (size_t)(row0 + wm * 128) * 1024 + col0 + wn * 64 + r32;
        #pragma unroll
        for (int mi = 0; mi < 4; ++mi)
            #pragma unroll
            for (int ni = 0; ni < 2; ++ni)
                #pragma unroll
                for (int reg = 0; reg < 16; ++reg) {
                    int rr = mi * 32 + (reg & 3) + 8 * (reg >> 2) + 4 * hw;
                    kp[(size_t)rr * 1024 + ni * 32] = f2bf(acc[mi][ni][reg]);
                }
    } else {
        // V half: Vt[(b*1024 + fv)*2048 + key], 4 consecutive keys per dwordx2
        const int bb = row0 >> 11;
        const int keybase = (row0 & 2047) + wm * 128 + 4 * hw;
        const int fvbase = col0 - 1024 + wn * 64 + r32;
        unsigned short* vp = Vt + ((size_t)bb * 1024 + fvbase) * 2048 + keybase;
        #pragma unroll
        for (int mi = 0; mi < 4; ++mi)
            #pragma unroll
            for (int ni = 0; ni < 2; ++ni)
                #pragma unroll
                for (int g = 0; g < 4; ++g) {
                    uint2 pk2;
                    pk2.x = pk_bf16(acc[mi][ni][g * 4 + 0], acc[mi][ni][g * 4 + 1]);
                    pk2.y = pk_bf16(acc[mi][ni][g * 4 + 2], acc[mi][ni][g * 4 + 3]);
                    *(uint2*)(vp + (size_t)(ni * 32) * 2048 + mi * 32 + g * 8) = pk2;
                }
    }
}

// ---------------- flash attention, S^T formulation, no-max softmax ----------------
// 256 q/block (64 q/wave, 4 subtiles of 16). S^T = K @ Q^T, PV as O^T = V^T @ P^T.
// K/V LDS double-buffered; next tile's global_load_lds issued BEFORE compute so the
// HBM/L2 latency hides under the 72 MFMAs (previously fully exposed between barriers).
// One __syncthreads per iter (its vmcnt(0) drain lands ~1 compute-phase after issue).
// l computed via ones-MFMA (A=1.0): k-reduction completes inside the matrix pipe.
// s_setprio(1) around MFMA clusters (T5).
// Grid (128 bh, 4 qtile): bh fastest => all qtiles of one (b,h) share an XCD slot (L2 reuse).
__global__ __launch_bounds__(256, 2) void attn_fwd(const unsigned short* __restrict__ qb,
                                                   const unsigned short* __restrict__ kb,
                                                   const unsigned short* __restrict__ vt,
                                                   unsigned short* __restrict__ ob) {
    constexpr int PSTR = 72;  // shorts; 144 B row stride, 16B-aligned
    __shared__ __align__(16) unsigned short lK[2][64 * 64];    // 2 x 8 KB, [key][d] XOR-swizzled
    __shared__ __align__(16) unsigned short lV[2][64 * 64];    // 2 x 8 KB, [d][key] XOR-swizzled
    __shared__ __align__(16) unsigned short lP[4][32 * PSTR];  // per-wave P[q(32)][key]
    const int tid = threadIdx.x;
    const int w = tid >> 6, l = tid & 63;
    const int bh = blockIdx.x;
    const int b = bh >> 4, h = bh & 15;
    const int q0 = blockIdx.y * 256;
    const int lrow = l & 15, lq = l >> 4;
    const int srow = l >> 3, scol = ((l & 7) ^ (srow & 7)) * 8;

    // Q as MFMA B-operand: n=q=lrow, k=d=kc*32+lq*8+j ; 4 q-subtiles per wave
    bf16x8 bq[4][2];
    #pragma unroll
    for (int qs = 0; qs < 4; ++qs)
        #pragma unroll
        for (int kc = 0; kc < 2; ++kc) {
            int row = b * 1024 + q0 + w * 64 + qs * 16 + lrow;
            int col = h * 64 + kc * 32 + lq * 8;
            bq[qs][kc] = *(const bf16x8*)(qb + (size_t)row * 1024 + col);
        }

    f32x4 ot[4][4];            // O^T frags: q=lrow, d=16*dt+4*lq+r
    f32x4 lfr[4];              // l accumulators via ones-MFMA (all regs equal per lane)
    #pragma unroll
    for (int qs = 0; qs < 4; ++qs) {
        #pragma unroll
        for (int dt = 0; dt < 4; ++dt) ot[qs][dt] = (f32x4)0.f;
        lfr[qs] = (f32x4)0.f;
    }
    bf16x8 one8;
    #pragma unroll
    for (int i = 0; i < 8; ++i) one8[i] = (bf16_t)1.0f;

    // hoisted LDS fragment pointers (buffer 0; buffer 1 = +8192 B)
    const char* kp0 = (const char*)lK + lrow * 128 + ((lq ^ (lrow & 7)) * 16);
    const char* kp1 = (const char*)lK + lrow * 128 + (((4 + lq) ^ (lrow & 7)) * 16);
    const char* vp0 = (const char*)lV + lrow * 128 + ((lq ^ (lrow & 7)) * 16);
    const char* vp1 = (const char*)lV + lrow * 128 + (((4 + lq) ^ (lrow & 7)) * 16);
    char* pw[2];
    const char* pr[2];
    #pragma unroll
    for (int u = 0; u < 2; ++u) {
        pw[u] = (char*)&lP[w][(u * 16 + lrow) * PSTR + 4 * lq];
        pr[u] = (const char*)&lP[w][(u * 16 + lrow) * PSTR + 8 * lq];
    }

    // running global staging pointers
    const unsigned short* gkp = kb + (size_t)b * 2048 * 1024 + h * 64 +
                                (size_t)(w * 8 + srow) * 1024 + scol;
    const unsigned short* gvp = vt + (size_t)(b * 1024 + h * 64) * 2048 +
                                (size_t)(w * 8 + srow) * 2048 + scol;
    char* lKw0 = (char*)lK + (w * 8) * 128;
    char* lKw1 = (char*)lK + (32 + w * 8) * 128;
    char* lVw0 = (char*)lV + (w * 8) * 128;
    char* lVw1 = (char*)lV + (32 + w * 8) * 128;

    // prologue: stage it=0 into buffer 0
    async_load16(gkp, lKw0);
    async_load16(gkp + 32 * 1024, lKw1);
    async_load16(gvp, lVw0);
    async_load16(gvp + 32 * 2048, lVw1);
    gkp += 64 * 1024;
    gvp += 64;
    __syncthreads();

    for (int it = 0; it < 32; ++it) {
        const int bo = (it & 1) * 8192;   // byte offset of current buffer
        // prefetch next K/V tile into the other buffer (issued before compute)
        if (it < 31) {
            const int bn = bo ^ 8192;
            async_load16(gkp, lKw0 + bn);
            async_load16(gkp + 32 * 1024, lKw1 + bn);
            async_load16(gvp, lVw0 + bn);
            async_load16(gvp + 32 * 2048, lVw1 + bn);
            gkp += 64 * 1024;
            gvp += 64;
        }

        // K and V frags once per iteration, reused across all 4 q-subtiles
        bf16x8 ka[4][2], va[4][2];
        #pragma unroll
        for (int mt = 0; mt < 4; ++mt) {
            ka[mt][0] = *(const bf16x8*)(kp0 + bo + mt * 2048);
            ka[mt][1] = *(const bf16x8*)(kp1 + bo + mt * 2048);
        }
        #pragma unroll
        for (int dt = 0; dt < 4; ++dt) {
            va[dt][0] = *(const bf16x8*)(vp0 + bo + dt * 2048);
            va[dt][1] = *(const bf16x8*)(vp1 + bo + dt * 2048);
        }

        #pragma unroll
        for (int p = 0; p < 2; ++p) {
            // S^T = K @ Q^T for the two q-subtiles of this pair
            f32x4 st[2][4];
            __builtin_amdgcn_s_setprio(1);
            #pragma unroll
            for (int u = 0; u < 2; ++u) {
                const int qs = 2 * p + u;
                #pragma unroll
                for (int mt = 0; mt < 4; ++mt) {
                    f32x4 c = (f32x4)0.f;
                    c = __builtin_amdgcn_mfma_f32_16x16x32_bf16(ka[mt][0], bq[qs][0], c, 0, 0, 0);
                    c = __builtin_amdgcn_mfma_f32_16x16x32_bf16(ka[mt][1], bq[qs][1], c, 0, 0, 0);
                    st[u][mt] = c;
                }
            }
            __builtin_amdgcn_s_setprio(0);
            // P = exp2(S), pack to wave-private LDS pair buffer
            #pragma unroll
            for (int u = 0; u < 2; ++u) {
                #pragma unroll
                for (int mt = 0; mt < 4; ++mt) {
                    #pragma unroll
                    for (int r = 0; r < 4; ++r)
                        st[u][mt][r] = __builtin_amdgcn_exp2f(st[u][mt][r]);
                    uint2 pk;
                    pk.x = pk_bf16(st[u][mt][0], st[u][mt][1]);
                    pk.y = pk_bf16(st[u][mt][2], st[u][mt][3]);
                    *(uint2*)(pw[u] + 32 * mt) = pk;
                }
            }
            // P^T as B-operand
            bf16x8 pb[2][2];
            #pragma unroll
            for (int u = 0; u < 2; ++u)
                #pragma unroll
                for (int kcg = 0; kcg < 2; ++kcg)
                    pb[u][kcg] = *(const bf16x8*)(pr[u] + 64 * kcg);
            // l += ones @ P^T (k-reduction inside MFMA), O^T += V^T @ P^T
            __builtin_amdgcn_s_setprio(1);
            #pragma unroll
            for (int u = 0; u < 2; ++u) {
                const int qs = 2 * p + u;
                lfr[qs] = __builtin_amdgcn_mfma_f32_16x16x32_bf16(one8, pb[u][0], lfr[qs], 0, 0, 0);
                lfr[qs] = __builtin_amdgcn_mfma_f32_16x16x32_bf16(one8, pb[u][1], lfr[qs], 0, 0, 0);
                #pragma unroll
                for (int dt = 0; dt < 4; ++dt) {
                    ot[qs][dt] = __builtin_amdgcn_mfma_f32_16x16x32_bf16(va[dt][0], pb[u][0], ot[qs][dt], 0, 0, 0);
                    ot[qs][dt] = __builtin_amdgcn_mfma_f32_16x16x32_bf16(va[dt][1], pb[u][1], ot[qs][dt], 0, 0, 0);
                }
            }
            __builtin_amdgcn_s_setprio(0);
        }
        __syncthreads();   // drains prefetch; all waves aligned for buffer swap
    }

    #pragma unroll
    for (int qs = 0; qs < 4; ++qs) {
        float inv = 1.f / lfr[qs][0];
        size_t grow = (size_t)(b * 1024 + q0 + w * 64 + qs * 16 + lrow);
        unsigned short* op = ob + grow * 1024 + h * 64 + 4 * lq;
        #pragma unroll
        for (int dt = 0; dt < 4; ++dt) {
            uint2 pk;
            pk.x = pk_bf16(ot[qs][dt][0] * inv, ot[qs][dt][1] * inv);
            pk.y = pk_bf16(ot[qs][dt][2] * inv, ot[qs][dt][3] * inv);
            *(uint2*)(op + 16 * dt) = pk;
        }
    }
}

extern "C" void kernel_launch(void* const* d_in, const int* in_sizes, int n_in,
                              void* d_out, int out_size, void* d_ws, size_t ws_size,
                              hipStream_t stream) {
    const float* query   = (const float*)d_in[0];   // [8,1024,1024]
    const float* context = (const float*)d_in[1];   // [8,2048,768]
    const float* w_q     = (const float*)d_in[2];   // [1024,1024]
    const float* w_kv    = (const float*)d_in[3];   // [768,2048]
    const float* w_out   = (const float*)d_in[4];   // [1024,1024]
    const float* b_out   = (const float*)d_in[5];   // [1024]
    float* out = (float*)d_out;

    char* p = (char*)d_ws;
    unsigned short* qin   = (unsigned short*)p; p += (size_t)8192 * 1024 * 2;
    unsigned short* cin   = (unsigned short*)p; p += (size_t)16384 * 768 * 2;
    unsigned short* wqT   = (unsigned short*)p; p += (size_t)1024 * 1024 * 2;
    unsigned short* wkvT  = (unsigned short*)p; p += (size_t)2048 * 768 * 2;
    unsigned short* woutT = (unsigned short*)p; p += (size_t)1024 * 1024 * 2;
    unsigned short* qproj = (unsigned short*)p; p += (size_t)8192 * 1024 * 2;
    unsigned short* kbuf  = (unsigned short*)p; p += (size_t)16384 * 1024 * 2;
    unsigned short* vT    = (unsigned short*)p; p += (size_t)16384 * 1024 * 2;
    unsigned short* obuf  = (unsigned short*)p; p += (size_t)8192 * 1024 * 2;

    const float qscale = 0.125f * 1.44269504088896f;  // SCALE * log2(e), folded into w_q

    cast_f32_bf16<<<8388608 / 8 / 256, 256, 0, stream>>>(query, qin, 8388608 / 8);
    cast_f32_bf16<<<12582912 / 8 / 256, 256, 0, stream>>>(context, cin, 12582912 / 8);
    transcast<<<dim3(32, 32), dim3(32, 8), 0, stream>>>(w_q, wqT, 1024, 1024, qscale);
    transcast<<<dim3(64, 24), dim3(32, 8), 0, stream>>>(w_kv, wkvT, 768, 2048, 1.0f);
    transcast<<<dim3(32, 32), dim3(32, 8), 0, stream>>>(w_out, woutT, 1024, 1024, 1.0f);
    // q = (query @ w_q) * qscale
    gemm_bt<0><<<dim3(8, 64), 256, 0, stream>>>(qin, wqT, qproj, nullptr, 1024, 1024, 16);
    // kv = context @ w_kv -> kbuf (K) + vT (V transposed to [d][key])
    gemm_kv<<<dim3(16, 64), 256, 0, stream>>>(cin, wkvT, kbuf, vT);
    // attention: grid x = (b,h) for XCD-local K/V reuse, y = 256-row q tiles
    attn_fwd<<<dim3(128, 4), 256, 0, stream>>>(qproj, kbuf, vT, obuf);
    // out = o @ w_out + b_out
    gemm_bt<2><<<dim3(8, 64), 256, 0, stream>>>(obuf, woutT, out, b_out, 1024, 1024, 16);
}

// Round 2
// 332.373 us; speedup vs baseline: 1.0523x; 1.0241x over previous
//
#include <hip/hip_runtime.h>
#include <stdint.h>

typedef __bf16 bf16_t;
typedef bf16_t bf16x8 __attribute__((ext_vector_type(8)));
typedef float f32x4 __attribute__((ext_vector_type(4)));
typedef float f32x16 __attribute__((ext_vector_type(16)));
typedef unsigned uint32x2_t __attribute__((ext_vector_type(2)));
typedef unsigned uint32x4_t __attribute__((ext_vector_type(4)));

__device__ __forceinline__ unsigned short f2bf(float x) {
    unsigned u = __builtin_bit_cast(unsigned, x);
    u = (u + 0x7FFFu + ((u >> 16) & 1u)) >> 16;   // RNE
    return (unsigned short)u;
}

// pack two fp32 -> bf16x2 (round-half-up): 2 adds + 1 v_perm
__device__ __forceinline__ unsigned pk_bf16(float lo, float hi) {
    unsigned u0 = __builtin_bit_cast(unsigned, lo) + 0x8000u;
    unsigned u1 = __builtin_bit_cast(unsigned, hi) + 0x8000u;
    return __builtin_amdgcn_perm(u1, u0, 0x07060302u);
}

// CK-pattern async global->LDS, 16B per lane. LDS dest must be wave-uniform.
__device__ __forceinline__ void async_load16(const void* g, void* lds) {
    auto* gp = reinterpret_cast<const __attribute__((address_space(1))) uint32_t*>(
        reinterpret_cast<uintptr_t>(g));
    auto* lp = reinterpret_cast<__attribute__((address_space(3))) uint32_t*>(
        reinterpret_cast<uintptr_t>(lds));
    __builtin_amdgcn_global_load_lds(gp, lp, 16, 0, 0);
}

// ---------------- cast fp32 -> bf16, 8 elems/thread ----------------
__global__ __launch_bounds__(256) void cast_f32_bf16(const float* __restrict__ src,
                                                     unsigned short* __restrict__ dst,
                                                     int n8) {
    int i = blockIdx.x * 256 + threadIdx.x;
    if (i >= n8) return;
    const float4* s4 = (const float4*)src;
    float4 a = s4[i * 2], b = s4[i * 2 + 1];
    uint4 o;
    o.x = (unsigned)f2bf(a.x) | ((unsigned)f2bf(a.y) << 16);
    o.y = (unsigned)f2bf(a.z) | ((unsigned)f2bf(a.w) << 16);
    o.z = (unsigned)f2bf(b.x) | ((unsigned)f2bf(b.y) << 16);
    o.w = (unsigned)f2bf(b.z) | ((unsigned)f2bf(b.w) << 16);
    ((uint4*)dst)[i] = o;
}

// ---------------- transpose-cast: src [K][N] fp32 -> dst [N][K] bf16, * scale ----------------
__global__ __launch_bounds__(256) void transcast(const float* __restrict__ src,
                                                 unsigned short* __restrict__ dst,
                                                 int K, int N, float scale) {
    __shared__ float tile[32][33];
    int x = threadIdx.x, y = threadIdx.y;          // block (32,8)
    int c0 = blockIdx.x * 32, r0 = blockIdx.y * 32;
    #pragma unroll
    for (int i = 0; i < 32; i += 8)
        tile[y + i][x] = src[(size_t)(r0 + y + i) * N + c0 + x];
    __syncthreads();
    #pragma unroll
    for (int i = 0; i < 32; i += 8)
        dst[(size_t)(c0 + y + i) * K + r0 + x] = f2bf(tile[x][y + i] * scale);
}

// ---------------- C = A[M,K] * Bt[N,K]^T, bf16 MFMA, 128x128 tile, BK=64 ----------------
// Double-buffered LDS, prefetch-next-before-compute (T3 minimal 2-phase).
// EPI 0: bf16 out, stride N.  EPI 2: f32 out + bias.
template <int EPI>
__global__ __launch_bounds__(256) void gemm_bt(const unsigned short* __restrict__ A,
                                               const unsigned short* __restrict__ Bt,
                                               void* __restrict__ Cout,
                                               const float* __restrict__ bias,
                                               int K, int N, int nkt) {
    __shared__ __align__(16) unsigned short lA[2][128 * 64];  // 2 x 16 KB
    __shared__ __align__(16) unsigned short lB[2][128 * 64];  // 2 x 16 KB
    const int tid = threadIdx.x;
    const int w = tid >> 6, l = tid & 63;
    const int wm = w >> 1, wn = w & 1;
    const int row0 = blockIdx.y * 128, col0 = blockIdx.x * 128;
    const int lrow = l & 15, lq = l >> 4;
    const int srow = l >> 3;                 // 0..7: row within an issue's 8-row group
    const int scol = ((l & 7) ^ srow) * 8;   // XOR-swizzled k-chunk (elems)

    f32x4 acc[4][4];
    #pragma unroll
    for (int i = 0; i < 4; ++i)
        #pragma unroll
        for (int j = 0; j < 4; ++j) acc[i][j] = (f32x4)0.f;

    // hoisted per-q global source pointers; advance by 64 elems per staged tile
    const unsigned short* ga[4];
    const unsigned short* gb[4];
    #pragma unroll
    for (int q = 0; q < 4; ++q) {
        const int r = (w * 4 + q) * 8 + srow;
        ga[q] = A + (size_t)(row0 + r) * K + scol;
        gb[q] = Bt + (size_t)(col0 + r) * K + scol;
    }

    // prologue: stage kt=0 into buffer 0
    #pragma unroll
    for (int q = 0; q < 4; ++q) {
        async_load16(ga[q], (char*)lA + (w * 4 + q) * 1024);
        async_load16(gb[q], (char*)lB + (w * 4 + q) * 1024);
        ga[q] += 64;
        gb[q] += 64;
    }
    __syncthreads();

    for (int kt = 0; kt < nkt; ++kt) {
        const int bo = (kt & 1) * 16384;   // byte offset of current buffer
        if (kt + 1 < nkt) {
            const int bn = bo ^ 16384;
            #pragma unroll
            for (int q = 0; q < 4; ++q) {
                async_load16(ga[q], (char*)lA + bn + (w * 4 + q) * 1024);
                async_load16(gb[q], (char*)lB + bn + (w * 4 + q) * 1024);
                ga[q] += 64;
                gb[q] += 64;
            }
        }
        #pragma unroll
        for (int kc = 0; kc < 2; ++kc) {
            const int pc = ((kc * 4 + lq) ^ (lrow & 7)) * 16;  // byte offset of chunk
            bf16x8 af[4], bfr[4];
            #pragma unroll
            for (int i = 0; i < 4; ++i)
                af[i] = *(const bf16x8*)((const char*)lA + bo + (wm * 64 + i * 16 + lrow) * 128 + pc);
            #pragma unroll
            for (int j = 0; j < 4; ++j)
                bfr[j] = *(const bf16x8*)((const char*)lB + bo + (wn * 64 + j * 16 + lrow) * 128 + pc);
            #pragma unroll
            for (int i = 0; i < 4; ++i)
                #pragma unroll
                for (int j = 0; j < 4; ++j)
                    acc[i][j] = __builtin_amdgcn_mfma_f32_16x16x32_bf16(af[i], bfr[j],
                                                                        acc[i][j], 0, 0, 0);
        }
        __syncthreads();   // drains prefetch vmcnt; issued ~1 compute-phase earlier
    }
    #pragma unroll
    for (int i = 0; i < 4; ++i) {
        const int grow0 = row0 + wm * 64 + i * 16 + lq * 4;
        #pragma unroll
        for (int j = 0; j < 4; ++j) {
            const int gcol = col0 + wn * 64 + j * 16 + lrow;
            #pragma unroll
            for (int r = 0; r < 4; ++r) {
                float v = acc[i][j][r];
                int grow = grow0 + r;
                if (EPI == 0) {
                    ((unsigned short*)Cout)[(size_t)grow * N + gcol] = f2bf(v);
                } else {
                    ((float*)Cout)[(size_t)grow * N + gcol] = v + bias[gcol];
                }
            }
        }
    }
}

// ---------------- KV GEMM: 256x128 block, 32x32x16 MFMA, wave tile 128x64 ----------------
// A = cin [16384 x 768], Bt = wkvT [2048 x 768], K=768 (12 BK=64 tiles).
// cols<1024 -> Kb[b*2048+key][feat]; cols>=1024 -> Vt[(b*1024+fv)][key] packed dwordx2.
__global__ __launch_bounds__(256, 2) void gemm_kv(const unsigned short* __restrict__ A,
                                                  const unsigned short* __restrict__ Bt,
                                                  unsigned short* __restrict__ Kb,
                                                  unsigned short* __restrict__ Vt) {
    __shared__ __align__(16) unsigned short lA[256 * 64];  // 32 KB
    __shared__ __align__(16) unsigned short lB[128 * 64];  // 16 KB
    const int tid = threadIdx.x;
    const int w = tid >> 6, l = tid & 63;
    const int wm = w >> 1, wn = w & 1;
    const int row0 = blockIdx.y * 256, col0 = blockIdx.x * 128;
    const int r32 = l & 31, hw = l >> 5;
    const int srow = l >> 3, scol = ((l & 7) ^ srow) * 8;

    f32x16 acc[4][2];
    #pragma unroll
    for (int mi = 0; mi < 4; ++mi)
        #pragma unroll
        for (int ni = 0; ni < 2; ++ni) acc[mi][ni] = (f32x16)0.f;

    const unsigned short* ga = A + (size_t)(row0 + w * 8 + srow) * 768 + scol;
    const unsigned short* gb = Bt + (size_t)(col0 + w * 8 + srow) * 768 + scol;
    char* lAw = (char*)lA + (w * 8) * 128;
    char* lBw = (char*)lB + (w * 8) * 128;
    const char* lap = (const char*)lA + (wm * 128 + r32) * 128;
    const char* lbp = (const char*)lB + (wn * 64 + r32) * 128;
    const int r7 = r32 & 7;

    for (int kt = 0; kt < 12; ++kt) {
        __syncthreads();
        #pragma unroll
        for (int q = 0; q < 8; ++q)
            async_load16(ga + (size_t)q * 32 * 768, lAw + q * 32 * 128);
        #pragma unroll
        for (int q = 0; q < 4; ++q)
            async_load16(gb + (size_t)q * 32 * 768, lBw + q * 32 * 128);
        ga += 64;
        gb += 64;
        __syncthreads();
        #pragma unroll
        for (int ks = 0; ks < 4; ++ks) {
            const int off = ((ks * 2 + hw) ^ r7) * 16;  // byte offset of swizzled chunk
            bf16x8 af[4], bfr[2];
            #pragma unroll
            for (int mi = 0; mi < 4; ++mi)
                af[mi] = *(const bf16x8*)(lap + mi * 32 * 128 + off);
            #pragma unroll
            for (int ni = 0; ni < 2; ++ni)
                bfr[ni] = *(const bf16x8*)(lbp + ni * 32 * 128 + off);
            #pragma unroll
            for (int mi = 0; mi < 4; ++mi)
                #pragma unroll
                for (int ni = 0; ni < 2; ++ni)
                    acc[mi][ni] = __builtin_amdgcn_mfma_f32_32x32x16_bf16(af[mi], bfr[ni],
                                                                          acc[mi][ni], 0, 0, 0);
        }
    }

    // C/D 32x32 layout: col = lane&31, row = (reg&3) + 8*(reg>>2) + 4*(lane>>5)
    if (col0 < 1024) {
        // K half: Kb[(row0 + wm*128 + rr) * 1024 + col0 + wn*64 + ni*32 + r32]
        unsigned short* kp = Kb + (size_t)(row0 + wm * 128) * 1024 + col0 + wn * 64 + r32;
        #pragma unroll
        for (int mi = 0; mi < 4; ++mi)
            #pragma unroll
            for (int ni = 0; ni < 2; ++ni)
                #pragma unroll
                for (int reg = 0; reg < 16; ++reg) {
                    int rr = mi * 32 + (reg & 3) + 8 * (reg >> 2) + 4 * hw;
                    kp[(size_t)rr * 1024 + ni * 32] = f2bf(acc[mi][ni][reg]);
                }
    } else {
        // V half: Vt[(b*1024 + fv)*2048 + key], 4 consecutive keys per dwordx2
        const int bb = row0 >> 11;
        const int keybase = (row0 & 2047) + wm * 128 + 4 * hw;
        const int fvbase = col0 - 1024 + wn * 64 + r32;
        unsigned short* vp = Vt + ((size_t)bb * 1024 + fvbase) * 2048 + keybase;
        #pragma unroll
        for (int mi = 0; mi < 4; ++mi)
            #pragma unroll
            for (int ni = 0; ni < 2; ++ni)
                #pragma unroll
                for (int g = 0; g < 4; ++g) {
                    uint2 pk2;
                    pk2.x = pk_bf16(acc[mi][ni][g * 4 + 0], acc[mi][ni][g * 4 + 1]);
                    pk2.y = pk_bf16(acc[mi][ni][g * 4 + 2], acc[mi][ni][g * 4 + 3]);
                    *(uint2*)(vp + (size_t)(ni * 32) * 2048 + mi * 32 + g * 8) = pk2;
                }
    }
}

// ---------------- flash attention, S^T formulation, no-max softmax ----------------
// 128 q/block (32 q/wave, 2 subtiles of 16), grid (128 bh, 8 qtile) = 1024 blocks
// = 4 blocks/CU, 4 waves/SIMD (2x the previous TLP to fill latency stalls).
// S^T = K @ Q^T, PV as O^T = V^T @ P^T.
// P^T produced IN-REGISTER via permlane32_swap + permlane16_swap (no LDS round-trip):
//   producer lane-group g holds P-dwords D[mt][r2] = keys mt*16+g*4+{2r2,2r2+1};
//   consumer group g' needs keys kcg*32+g'*8+2*j2;
//   pb[kcg] slot j2: Zj2 where (Z_{r2}, Z_{r2+2}) = permlane16_swap(permlane32_swap(D[2kcg? ..])):
//   exactly: for pair (D[m][r2], D[m+1][r2]) with m in {0,2}:
//     t = permlane32_swap(Dm, Dm+1); (z_lo, z_hi) = permlane16_swap(t.x, t.y)
//     z_lo -> pb[m/2] slot r2, z_hi -> pb[m/2] slot r2+2   (index-verified)
// l computed via ones-MFMA. K/V LDS double-buffered, prefetch-before-compute,
// one barrier/iter. Same-bh blocks share an XCD slot (x fastest, 128 % 8 == 0).
__global__ __launch_bounds__(256, 4) void attn_fwd(const unsigned short* __restrict__ qb,
                                                   const unsigned short* __restrict__ kb,
                                                   const unsigned short* __restrict__ vt,
                                                   unsigned short* __restrict__ ob) {
    __shared__ __align__(16) unsigned short lK[2][64 * 64];    // 2 x 8 KB, [key][d] XOR-swizzled
    __shared__ __align__(16) unsigned short lV[2][64 * 64];    // 2 x 8 KB, [d][key] XOR-swizzled
    const int tid = threadIdx.x;
    const int w = tid >> 6, l = tid & 63;
    const int bh = blockIdx.x;
    const int b = bh >> 4, h = bh & 15;
    const int q0 = blockIdx.y * 128;
    const int lrow = l & 15, lq = l >> 4;
    const int srow = l >> 3, scol = ((l & 7) ^ (srow & 7)) * 8;

    // Q as MFMA B-operand: n=q=lrow, k=d=kc*32+lq*8+j ; 2 q-subtiles per wave
    bf16x8 bq[2][2];
    #pragma unroll
    for (int u = 0; u < 2; ++u)
        #pragma unroll
        for (int kc = 0; kc < 2; ++kc) {
            int row = b * 1024 + q0 + w * 32 + u * 16 + lrow;
            int col = h * 64 + kc * 32 + lq * 8;
            bq[u][kc] = *(const bf16x8*)(qb + (size_t)row * 1024 + col);
        }

    f32x4 ot[2][4];            // O^T frags: q=lrow, d=16*dt+4*lq+r
    f32x4 lfr[2];              // l accumulators via ones-MFMA (all regs equal per lane)
    #pragma unroll
    for (int u = 0; u < 2; ++u) {
        #pragma unroll
        for (int dt = 0; dt < 4; ++dt) ot[u][dt] = (f32x4)0.f;
        lfr[u] = (f32x4)0.f;
    }
    bf16x8 one8;
    #pragma unroll
    for (int i = 0; i < 8; ++i) one8[i] = (bf16_t)1.0f;

    // hoisted LDS fragment pointers (buffer 0; buffer 1 = +8192 B)
    const char* kp0 = (const char*)lK + lrow * 128 + ((lq ^ (lrow & 7)) * 16);
    const char* kp1 = (const char*)lK + lrow * 128 + (((4 + lq) ^ (lrow & 7)) * 16);
    const char* vp0 = (const char*)lV + lrow * 128 + ((lq ^ (lrow & 7)) * 16);
    const char* vp1 = (const char*)lV + lrow * 128 + (((4 + lq) ^ (lrow & 7)) * 16);

    // running global staging pointers
    const unsigned short* gkp = kb + (size_t)b * 2048 * 1024 + h * 64 +
                                (size_t)(w * 8 + srow) * 1024 + scol;
    const unsigned short* gvp = vt + (size_t)(b * 1024 + h * 64) * 2048 +
                                (size_t)(w * 8 + srow) * 2048 + scol;
    char* lKw0 = (char*)lK + (w * 8) * 128;
    char* lKw1 = (char*)lK + (32 + w * 8) * 128;
    char* lVw0 = (char*)lV + (w * 8) * 128;
    char* lVw1 = (char*)lV + (32 + w * 8) * 128;

    // prologue: stage it=0 into buffer 0
    async_load16(gkp, lKw0);
    async_load16(gkp + 32 * 1024, lKw1);
    async_load16(gvp, lVw0);
    async_load16(gvp + 32 * 2048, lVw1);
    gkp += 64 * 1024;
    gvp += 64;
    __syncthreads();

    for (int it = 0; it < 32; ++it) {
        const int bo = (it & 1) * 8192;   // byte offset of current buffer
        // prefetch next K/V tile into the other buffer (issued before compute)
        if (it < 31) {
            const int bn = bo ^ 8192;
            async_load16(gkp, lKw0 + bn);
            async_load16(gkp + 32 * 1024, lKw1 + bn);
            async_load16(gvp, lVw0 + bn);
            async_load16(gvp + 32 * 2048, lVw1 + bn);
            gkp += 64 * 1024;
            gvp += 64;
        }

        // K frags for this tile
        bf16x8 ka[4][2];
        #pragma unroll
        for (int mt = 0; mt < 4; ++mt) {
            ka[mt][0] = *(const bf16x8*)(kp0 + bo + mt * 2048);
            ka[mt][1] = *(const bf16x8*)(kp1 + bo + mt * 2048);
        }

        // S^T = K @ Q^T ; exp2 ; pack to dwords immediately (st transient)
        unsigned D[2][4][2];
        __builtin_amdgcn_s_setprio(1);
        #pragma unroll
        for (int u = 0; u < 2; ++u) {
            #pragma unroll
            for (int mt = 0; mt < 4; ++mt) {
                f32x4 c = (f32x4)0.f;
                c = __builtin_amdgcn_mfma_f32_16x16x32_bf16(ka[mt][0], bq[u][0], c, 0, 0, 0);
                c = __builtin_amdgcn_mfma_f32_16x16x32_bf16(ka[mt][1], bq[u][1], c, 0, 0, 0);
                #pragma unroll
                for (int r = 0; r < 4; ++r)
                    c[r] = __builtin_amdgcn_exp2f(c[r]);
                D[u][mt][0] = pk_bf16(c[0], c[1]);
                D[u][mt][1] = pk_bf16(c[2], c[3]);
            }
        }
        __builtin_amdgcn_s_setprio(0);

        // in-register S^T -> P^T transpose within 4-lane groups {l, l+16, l+32, l+48}
        bf16x8 pb[2][2];   // [u][kcg]
        #pragma unroll
        for (int u = 0; u < 2; ++u) {
            uint32x4_t pbw[2];
            #pragma unroll
            for (int half = 0; half < 2; ++half) {     // half 0 -> mt{0,1} -> pb[0]; 1 -> mt{2,3} -> pb[1]
                #pragma unroll
                for (int r2 = 0; r2 < 2; ++r2) {
                    uint32x2_t t = __builtin_amdgcn_permlane32_swap(
                        D[u][half * 2][r2], D[u][half * 2 + 1][r2], false, false);
                    uint32x2_t z = __builtin_amdgcn_permlane16_swap(t.x, t.y, false, false);
                    pbw[half][r2] = z.x;        // slot j2 = r2
                    pbw[half][r2 + 2] = z.y;    // slot j2 = r2+2
                }
            }
            pb[u][0] = __builtin_bit_cast(bf16x8, pbw[0]);
            pb[u][1] = __builtin_bit_cast(bf16x8, pbw[1]);
        }

        // V frags (read after QK so ka regs are dead first)
        bf16x8 va[4][2];
        #pragma unroll
        for (int dt = 0; dt < 4; ++dt) {
            va[dt][0] = *(const bf16x8*)(vp0 + bo + dt * 2048);
            va[dt][1] = *(const bf16x8*)(vp1 + bo + dt * 2048);
        }

        // l += ones @ P^T (k-reduction inside MFMA), O^T += V^T @ P^T
        __builtin_amdgcn_s_setprio(1);
        #pragma unroll
        for (int u = 0; u < 2; ++u) {
            lfr[u] = __builtin_amdgcn_mfma_f32_16x16x32_bf16(one8, pb[u][0], lfr[u], 0, 0, 0);
            lfr[u] = __builtin_amdgcn_mfma_f32_16x16x32_bf16(one8, pb[u][1], lfr[u], 0, 0, 0);
            #pragma unroll
            for (int dt = 0; dt < 4; ++dt) {
                ot[u][dt] = __builtin_amdgcn_mfma_f32_16x16x32_bf16(va[dt][0], pb[u][0], ot[u][dt], 0, 0, 0);
                ot[u][dt] = __builtin_amdgcn_mfma_f32_16x16x32_bf16(va[dt][1], pb[u][1], ot[u][dt], 0, 0, 0);
            }
        }
        __builtin_amdgcn_s_setprio(0);
        __syncthreads();   // drains prefetch; all waves aligned for buffer swap
    }

    #pragma unroll
    for (int u = 0; u < 2; ++u) {
        float inv = 1.f / lfr[u][0];
        size_t grow = (size_t)(b * 1024 + q0 + w * 32 + u * 16 + lrow);
        unsigned short* op = ob + grow * 1024 + h * 64 + 4 * lq;
        #pragma unroll
        for (int dt = 0; dt < 4; ++dt) {
            uint2 pk;
            pk.x = pk_bf16(ot[u][dt][0] * inv, ot[u][dt][1] * inv);
            pk.y = pk_bf16(ot[u][dt][2] * inv, ot[u][dt][3] * inv);
            *(uint2*)(op + 16 * dt) = pk;
        }
    }
}

extern "C" void kernel_launch(void* const* d_in, const int* in_sizes, int n_in,
                              void* d_out, int out_size, void* d_ws, size_t ws_size,
                              hipStream_t stream) {
    const float* query   = (const float*)d_in[0];   // [8,1024,1024]
    const float* context = (const float*)d_in[1];   // [8,2048,768]
    const float* w_q     = (const float*)d_in[2];   // [1024,1024]
    const float* w_kv    = (const float*)d_in[3];   // [768,2048]
    const float* w_out   = (const float*)d_in[4];   // [1024,1024]
    const float* b_out   = (const float*)d_in[5];   // [1024]
    float* out = (float*)d_out;

    char* p = (char*)d_ws;
    unsigned short* qin   = (unsigned short*)p; p += (size_t)8192 * 1024 * 2;
    unsigned short* cin   = (unsigned short*)p; p += (size_t)16384 * 768 * 2;
    unsigned short* wqT   = (unsigned short*)p; p += (size_t)1024 * 1024 * 2;
    unsigned short* wkvT  = (unsigned short*)p; p += (size_t)2048 * 768 * 2;
    unsigned short* woutT = (unsigned short*)p; p += (size_t)1024 * 1024 * 2;
    unsigned short* qproj = (unsigned short*)p; p += (size_t)8192 * 1024 * 2;
    unsigned short* kbuf  = (unsigned short*)p; p += (size_t)16384 * 1024 * 2;
    unsigned short* vT    = (unsigned short*)p; p += (size_t)16384 * 1024 * 2;
    unsigned short* obuf  = (unsigned short*)p; p += (size_t)8192 * 1024 * 2;

    const float qscale = 0.125f * 1.44269504088896f;  // SCALE * log2(e), folded into w_q

    cast_f32_bf16<<<8388608 / 8 / 256, 256, 0, stream>>>(query, qin, 8388608 / 8);
    cast_f32_bf16<<<12582912 / 8 / 256, 256, 0, stream>>>(context, cin, 12582912 / 8);
    transcast<<<dim3(32, 32), dim3(32, 8), 0, stream>>>(w_q, wqT, 1024, 1024, qscale);
    transcast<<<dim3(64, 24), dim3(32, 8), 0, stream>>>(w_kv, wkvT, 768, 2048, 1.0f);
    transcast<<<dim3(32, 32), dim3(32, 8), 0, stream>>>(w_out, woutT, 1024, 1024, 1.0f);
    // q = (query @ w_q) * qscale
    gemm_bt<0><<<dim3(8, 64), 256, 0, stream>>>(qin, wqT, qproj, nullptr, 1024, 1024, 16);
    // kv = context @ w_kv -> kbuf (K) + vT (V transposed to [d][key])
    gemm_kv<<<dim3(16, 64), 256, 0, stream>>>(cin, wkvT, kbuf, vT);
    // attention: grid x = (b,h) for XCD-local K/V reuse, y = 128-row q tiles
    attn_fwd<<<dim3(128, 8), 256, 0, stream>>>(qproj, kbuf, vT, obuf);
    // out = o @ w_out + b_out
    gemm_bt<2><<<dim3(8, 64), 256, 0, stream>>>(obuf, woutT, out, b_out, 1024, 1024, 16);
}